// Round 9
// baseline (310.330 us; speedup 1.0000x reference)
//
#include <hip/hip_runtime.h>
#include <hip/hip_fp16.h>
#include <math.h>

#define D 128
#define PADH 136  // LDS row stride in halves (272 B = 17*16: b128-aligned, 2-way bank alias only)

typedef __attribute__((ext_vector_type(8))) _Float16 half8;
typedef __attribute__((ext_vector_type(4))) float f32x4;

// ---------------- prep: WhT[l][n][k] = (half)Wl[k][n]  +  cnt zeroing ----------------

__global__ void prep_kernel(const float* __restrict__ W1, const float* __restrict__ W2,
                            const float* __restrict__ W3, __half* __restrict__ WhT,
                            int* __restrict__ cnt, int N) {
    int i = blockIdx.x * blockDim.x + threadIdx.x;
    if (i < 3 * D * D) {
        int l = i >> 14, j = i & 16383, n = j >> 7, k = j & 127;
        const float* W = (l == 0) ? W1 : (l == 1) ? W2 : W3;
        WhT[(size_t)i] = __float2half(W[(size_t)k * D + n]);
    }
    if (i < N) cnt[i] = 0;
}

// ---------------- count+rank  ||  unscaled gemm1 (fused by block range) ----------------
// Blocks [0, CB): rank[e] = arrival order within dst bucket, cnt[d] = in-degree.
// Blocks [CB, ..): ysf = X @ W1 (fp32, UNSCALED -> no dependency on the graph build;
// the dinv scaling is applied bit-identically in fill_scale_kernel).

__global__ __launch_bounds__(256) void count_gemm1_kernel(
    const int* __restrict__ dst, int* __restrict__ cnt, int* __restrict__ rank,
    int E, int count_blocks,
    const float* __restrict__ X, const __half* __restrict__ WhT,
    float* __restrict__ Yf, int M) {
    int tid = threadIdx.x;
    if ((int)blockIdx.x < count_blocks) {
        const int NO = (E + 7) / 8;
        const int stride = count_blocks * 256;
        for (int c = blockIdx.x * 256 + tid; c < NO; c += stride) {
            int e0 = c * 8;
            if (e0 + 7 < E) {
                int4 da = *(const int4*)(dst + e0);
                int4 db = *(const int4*)(dst + e0 + 4);
                int4 ra, rb;
                ra.x = atomicAdd(&cnt[da.x], 1);
                ra.y = atomicAdd(&cnt[da.y], 1);
                ra.z = atomicAdd(&cnt[da.z], 1);
                ra.w = atomicAdd(&cnt[da.w], 1);
                rb.x = atomicAdd(&cnt[db.x], 1);
                rb.y = atomicAdd(&cnt[db.y], 1);
                rb.z = atomicAdd(&cnt[db.z], 1);
                rb.w = atomicAdd(&cnt[db.w], 1);
                *(int4*)(rank + e0)     = ra;
                *(int4*)(rank + e0 + 4) = rb;
            } else {
                for (int e = e0; e < E; ++e) rank[e] = atomicAdd(&cnt[dst[e]], 1);
            }
        }
        return;
    }
    int bid  = blockIdx.x - count_blocks;
    int wave = tid >> 6;
    int lane = tid & 63;
    int quad = lane >> 4;
    int l16  = lane & 15;
    int m0   = bid * 64 + wave * 16;
    if (m0 >= M) return;

    f32x4 acc[8];
    #pragma unroll
    for (int t = 0; t < 8; ++t) acc[t] = (f32x4)0.0f;
    const float* xrow = X + (size_t)(m0 + l16) * D;
    #pragma unroll
    for (int ks = 0; ks < 4; ++ks) {
        int k0 = ks * 32 + quad * 8;
        float4 x0 = *(const float4*)(xrow + k0);
        float4 x1 = *(const float4*)(xrow + k0 + 4);
        half8 a;
        a[0] = (_Float16)x0.x; a[1] = (_Float16)x0.y;
        a[2] = (_Float16)x0.z; a[3] = (_Float16)x0.w;
        a[4] = (_Float16)x1.x; a[5] = (_Float16)x1.y;
        a[6] = (_Float16)x1.z; a[7] = (_Float16)x1.w;
        #pragma unroll
        for (int t = 0; t < 8; ++t) {
            half8 b = *(const half8*)(WhT + (size_t)(t * 16 + l16) * D + k0);
            acc[t] = __builtin_amdgcn_mfma_f32_16x16x32_f16(a, b, acc[t], 0, 0, 0);
        }
    }
    #pragma unroll
    for (int t = 0; t < 8; ++t) {
        #pragma unroll
        for (int r = 0; r < 4; ++r) {
            int grow = m0 + quad * 4 + r;
            Yf[(size_t)grow * D + t * 16 + l16] = acc[t][r];
        }
    }
}

// ---------------- single-block scan: cnt -> rowptr, dinv ----------------

__global__ __launch_bounds__(1024) void scan_kernel(const int* __restrict__ cnt,
                                                    int* __restrict__ rowptr,
                                                    float* __restrict__ dinv,
                                                    int N) {
    __shared__ int wsum[16];
    int tid  = threadIdx.x;
    int lane = tid & 63;
    int wid  = tid >> 6;
    int C = ((N + 4095) / 4096) * 4;
    int start = tid * C;
    int end   = start + C; if (end > N) end = N;

    int local = 0;
    int i = start;
    for (; i + 3 < end; i += 4) {
        int4 v = *(const int4*)(cnt + i);
        local += v.x + v.y + v.z + v.w;
    }
    for (; i < end; ++i) local += cnt[i];

    int sc = local;
    #pragma unroll
    for (int off = 1; off < 64; off <<= 1) {
        int t = __shfl_up(sc, off, 64);
        if (lane >= off) sc += t;
    }
    if (lane == 63) wsum[wid] = sc;
    __syncthreads();
    if (tid < 16) {
        int w = wsum[tid];
        #pragma unroll
        for (int off = 1; off < 16; off <<= 1) {
            int t = __shfl_up(w, off, 16);
            if (tid >= off) w += t;
        }
        wsum[tid] = w;
    }
    __syncthreads();
    int run = ((wid > 0) ? wsum[wid - 1] : 0) + (sc - local);

    i = start;
    for (; i + 3 < end; i += 4) {
        int4 v = *(const int4*)(cnt + i);
        int4 rp;
        rp.x = run; rp.y = rp.x + v.x; rp.z = rp.y + v.y; rp.w = rp.z + v.z;
        run = rp.w + v.w;
        *(int4*)(rowptr + i) = rp;
        float4 dv;
        dv.x = rsqrtf((float)v.x + 1.0f);
        dv.y = rsqrtf((float)v.y + 1.0f);
        dv.z = rsqrtf((float)v.z + 1.0f);
        dv.w = rsqrtf((float)v.w + 1.0f);
        *(float4*)(dinv + i) = dv;
    }
    for (; i < end; ++i) {
        int v = cnt[i];
        rowptr[i] = run; run += v;
        dinv[i] = rsqrtf((float)v + 1.0f);
    }
    if (tid == 0) rowptr[N] = wsum[15];
}

// ---------------- sharded fill  ||  ys = fp16(ysf * dinv) (fused by block range) ----------------
// fill (blocks [0,FB)): shard = bid&7 rides the round-robin block->XCD map so each
// col line is written from exactly ONE XCD. scale (blocks [FB, FB+SB)): streaming,
// bit-identical to the old in-gemm scaling (fp32 multiply then single fp16 round).

__global__ __launch_bounds__(256) void fill_scale_kernel(
    const int* __restrict__ src, const int* __restrict__ dst,
    const int* __restrict__ rank, const int* __restrict__ rowptr,
    int* __restrict__ col, int E, int fill_blocks, int N,
    const float* __restrict__ Yf, const float* __restrict__ dinv,
    __half* __restrict__ Y, int scale_blocks) {
    int tid = threadIdx.x;
    if ((int)blockIdx.x < fill_blocks) {
        int shard = blockIdx.x & 7;
        int sub   = blockIdx.x >> 3;
        int nsub  = fill_blocks >> 3;
        int chunk = (N + 7) >> 3;
        int lo = shard * chunk;
        unsigned span = (unsigned)(min(lo + chunk, N) - lo);
        const int NO = (E + 7) / 8;
        for (int c = sub * 256 + tid; c < NO; c += nsub * 256) {
            int e0 = c * 8;
            if (e0 + 7 < E) {
                int4 da = *(const int4*)(dst + e0);
                int4 db = *(const int4*)(dst + e0 + 4);
                bool i0 = (unsigned)(da.x - lo) < span, i1 = (unsigned)(da.y - lo) < span;
                bool i2 = (unsigned)(da.z - lo) < span, i3 = (unsigned)(da.w - lo) < span;
                bool i4 = (unsigned)(db.x - lo) < span, i5 = (unsigned)(db.y - lo) < span;
                bool i6 = (unsigned)(db.z - lo) < span, i7 = (unsigned)(db.w - lo) < span;
                if (i0 | i1 | i2 | i3 | i4 | i5 | i6 | i7) {
                    int4 ra = *(const int4*)(rank + e0);
                    int4 rb = *(const int4*)(rank + e0 + 4);
                    int4 sa = *(const int4*)(src + e0);
                    int4 sb = *(const int4*)(src + e0 + 4);
                    if (i0) col[rowptr[da.x] + ra.x] = sa.x;
                    if (i1) col[rowptr[da.y] + ra.y] = sa.y;
                    if (i2) col[rowptr[da.z] + ra.z] = sa.z;
                    if (i3) col[rowptr[da.w] + ra.w] = sa.w;
                    if (i4) col[rowptr[db.x] + rb.x] = sb.x;
                    if (i5) col[rowptr[db.y] + rb.y] = sb.y;
                    if (i6) col[rowptr[db.z] + rb.z] = sb.z;
                    if (i7) col[rowptr[db.w] + rb.w] = sb.w;
                }
            } else {
                for (int e = e0; e < E; ++e) {
                    int d = dst[e];
                    if ((unsigned)(d - lo) < span) col[rowptr[d] + rank[e]] = src[e];
                }
            }
        }
        return;
    }
    // scale: each thread handles 8 consecutive elements of a row
    int sb = blockIdx.x - fill_blocks;
    const int nchunk = N * 16;
    const int stride = scale_blocks * 256;
    for (int i = sb * 256 + tid; i < nchunk; i += stride) {
        int row = i >> 4;
        int c8  = (i & 15) * 8;
        const float* p = Yf + (size_t)row * D + c8;
        float4 x0 = *(const float4*)p;
        float4 x1 = *(const float4*)(p + 4);
        float dv = dinv[row];
        half8 h;
        h[0] = (_Float16)(x0.x * dv); h[1] = (_Float16)(x0.y * dv);
        h[2] = (_Float16)(x0.z * dv); h[3] = (_Float16)(x0.w * dv);
        h[4] = (_Float16)(x1.x * dv); h[5] = (_Float16)(x1.y * dv);
        h[6] = (_Float16)(x1.z * dv); h[7] = (_Float16)(x1.w * dv);
        *(half8*)(Y + (size_t)row * D + c8) = h;
    }
}

// ---------------- quad-row gather, 16-deep unroll ----------------
// Lanes split 4 groups x 16; group g owns one row, lane holds 8 halves (16B).
// One instruction fetches FOUR rows' 256B lines; full-chunk 16-deep unroll keeps
// up to 64 row-lines in flight per wave.

__device__ __forceinline__ void gather4(const __half* __restrict__ g,
                                        const int* __restrict__ rowptr,
                                        const int* __restrict__ col,
                                        int row, int lane, float* __restrict__ acc) {
    int grp = lane >> 4;
    int l16 = lane & 15;
    int gb  = grp << 4;
    int s = rowptr[row], e = rowptr[row + 1];

    half8 hs = ((const half8*)(g + (size_t)row * D))[l16];
    float a0 = (float)hs[0], a1 = (float)hs[1], a2 = (float)hs[2], a3 = (float)hs[3];
    float a4 = (float)hs[4], a5 = (float)hs[5], a6 = (float)hs[6], a7 = (float)hs[7];
    float b0 = 0.f, b1 = 0.f, b2 = 0.f, b3 = 0.f, b4 = 0.f, b5 = 0.f, b6 = 0.f, b7 = 0.f;

    for (int base = s; base < e; base += 16) {
        int idx = base + l16;
        int myc = (idx < e) ? col[idx] : 0;
        int nb  = min(16, e - base);
        if (nb == 16) {
            int c0 = __shfl(myc, gb + 0),  c1 = __shfl(myc, gb + 1);
            int c2 = __shfl(myc, gb + 2),  c3 = __shfl(myc, gb + 3);
            int c4 = __shfl(myc, gb + 4),  c5 = __shfl(myc, gb + 5);
            int c6 = __shfl(myc, gb + 6),  c7 = __shfl(myc, gb + 7);
            int c8 = __shfl(myc, gb + 8),  c9 = __shfl(myc, gb + 9);
            int cA = __shfl(myc, gb + 10), cB = __shfl(myc, gb + 11);
            int cC = __shfl(myc, gb + 12), cD = __shfl(myc, gb + 13);
            int cE = __shfl(myc, gb + 14), cF = __shfl(myc, gb + 15);
            half8 v0 = ((const half8*)(g + (size_t)c0 * D))[l16];
            half8 v1 = ((const half8*)(g + (size_t)c1 * D))[l16];
            half8 v2 = ((const half8*)(g + (size_t)c2 * D))[l16];
            half8 v3 = ((const half8*)(g + (size_t)c3 * D))[l16];
            half8 v4 = ((const half8*)(g + (size_t)c4 * D))[l16];
            half8 v5 = ((const half8*)(g + (size_t)c5 * D))[l16];
            half8 v6 = ((const half8*)(g + (size_t)c6 * D))[l16];
            half8 v7 = ((const half8*)(g + (size_t)c7 * D))[l16];
            half8 v8 = ((const half8*)(g + (size_t)c8 * D))[l16];
            half8 v9 = ((const half8*)(g + (size_t)c9 * D))[l16];
            half8 vA = ((const half8*)(g + (size_t)cA * D))[l16];
            half8 vB = ((const half8*)(g + (size_t)cB * D))[l16];
            half8 vC = ((const half8*)(g + (size_t)cC * D))[l16];
            half8 vD = ((const half8*)(g + (size_t)cD * D))[l16];
            half8 vE = ((const half8*)(g + (size_t)cE * D))[l16];
            half8 vF = ((const half8*)(g + (size_t)cF * D))[l16];
            a0 += (float)v0[0]; a1 += (float)v0[1]; a2 += (float)v0[2]; a3 += (float)v0[3];
            a4 += (float)v0[4]; a5 += (float)v0[5]; a6 += (float)v0[6]; a7 += (float)v0[7];
            b0 += (float)v1[0]; b1 += (float)v1[1]; b2 += (float)v1[2]; b3 += (float)v1[3];
            b4 += (float)v1[4]; b5 += (float)v1[5]; b6 += (float)v1[6]; b7 += (float)v1[7];
            a0 += (float)v2[0]; a1 += (float)v2[1]; a2 += (float)v2[2]; a3 += (float)v2[3];
            a4 += (float)v2[4]; a5 += (float)v2[5]; a6 += (float)v2[6]; a7 += (float)v2[7];
            b0 += (float)v3[0]; b1 += (float)v3[1]; b2 += (float)v3[2]; b3 += (float)v3[3];
            b4 += (float)v3[4]; b5 += (float)v3[5]; b6 += (float)v3[6]; b7 += (float)v3[7];
            a0 += (float)v4[0]; a1 += (float)v4[1]; a2 += (float)v4[2]; a3 += (float)v4[3];
            a4 += (float)v4[4]; a5 += (float)v4[5]; a6 += (float)v4[6]; a7 += (float)v4[7];
            b0 += (float)v5[0]; b1 += (float)v5[1]; b2 += (float)v5[2]; b3 += (float)v5[3];
            b4 += (float)v5[4]; b5 += (float)v5[5]; b6 += (float)v5[6]; b7 += (float)v5[7];
            a0 += (float)v6[0]; a1 += (float)v6[1]; a2 += (float)v6[2]; a3 += (float)v6[3];
            a4 += (float)v6[4]; a5 += (float)v6[5]; a6 += (float)v6[6]; a7 += (float)v6[7];
            b0 += (float)v7[0]; b1 += (float)v7[1]; b2 += (float)v7[2]; b3 += (float)v7[3];
            b4 += (float)v7[4]; b5 += (float)v7[5]; b6 += (float)v7[6]; b7 += (float)v7[7];
            a0 += (float)v8[0]; a1 += (float)v8[1]; a2 += (float)v8[2]; a3 += (float)v8[3];
            a4 += (float)v8[4]; a5 += (float)v8[5]; a6 += (float)v8[6]; a7 += (float)v8[7];
            b0 += (float)v9[0]; b1 += (float)v9[1]; b2 += (float)v9[2]; b3 += (float)v9[3];
            b4 += (float)v9[4]; b5 += (float)v9[5]; b6 += (float)v9[6]; b7 += (float)v9[7];
            a0 += (float)vA[0]; a1 += (float)vA[1]; a2 += (float)vA[2]; a3 += (float)vA[3];
            a4 += (float)vA[4]; a5 += (float)vA[5]; a6 += (float)vA[6]; a7 += (float)vA[7];
            b0 += (float)vB[0]; b1 += (float)vB[1]; b2 += (float)vB[2]; b3 += (float)vB[3];
            b4 += (float)vB[4]; b5 += (float)vB[5]; b6 += (float)vB[6]; b7 += (float)vB[7];
            a0 += (float)vC[0]; a1 += (float)vC[1]; a2 += (float)vC[2]; a3 += (float)vC[3];
            a4 += (float)vC[4]; a5 += (float)vC[5]; a6 += (float)vC[6]; a7 += (float)vC[7];
            b0 += (float)vD[0]; b1 += (float)vD[1]; b2 += (float)vD[2]; b3 += (float)vD[3];
            b4 += (float)vD[4]; b5 += (float)vD[5]; b6 += (float)vD[6]; b7 += (float)vD[7];
            a0 += (float)vE[0]; a1 += (float)vE[1]; a2 += (float)vE[2]; a3 += (float)vE[3];
            a4 += (float)vE[4]; a5 += (float)vE[5]; a6 += (float)vE[6]; a7 += (float)vE[7];
            b0 += (float)vF[0]; b1 += (float)vF[1]; b2 += (float)vF[2]; b3 += (float)vF[3];
            b4 += (float)vF[4]; b5 += (float)vF[5]; b6 += (float)vF[6]; b7 += (float)vF[7];
        } else {
            int j = 0;
            for (; j + 4 <= nb; j += 4) {
                int c0 = __shfl(myc, gb + j + 0), c1 = __shfl(myc, gb + j + 1);
                int c2 = __shfl(myc, gb + j + 2), c3 = __shfl(myc, gb + j + 3);
                half8 v0 = ((const half8*)(g + (size_t)c0 * D))[l16];
                half8 v1 = ((const half8*)(g + (size_t)c1 * D))[l16];
                half8 v2 = ((const half8*)(g + (size_t)c2 * D))[l16];
                half8 v3 = ((const half8*)(g + (size_t)c3 * D))[l16];
                a0 += (float)v0[0]; a1 += (float)v0[1]; a2 += (float)v0[2]; a3 += (float)v0[3];
                a4 += (float)v0[4]; a5 += (float)v0[5]; a6 += (float)v0[6]; a7 += (float)v0[7];
                b0 += (float)v1[0]; b1 += (float)v1[1]; b2 += (float)v1[2]; b3 += (float)v1[3];
                b4 += (float)v1[4]; b5 += (float)v1[5]; b6 += (float)v1[6]; b7 += (float)v1[7];
                a0 += (float)v2[0]; a1 += (float)v2[1]; a2 += (float)v2[2]; a3 += (float)v2[3];
                a4 += (float)v2[4]; a5 += (float)v2[5]; a6 += (float)v2[6]; a7 += (float)v2[7];
                b0 += (float)v3[0]; b1 += (float)v3[1]; b2 += (float)v3[2]; b3 += (float)v3[3];
                b4 += (float)v3[4]; b5 += (float)v3[5]; b6 += (float)v3[6]; b7 += (float)v3[7];
            }
            for (; j < nb; ++j) {
                int c = __shfl(myc, gb + j);
                half8 v = ((const half8*)(g + (size_t)c * D))[l16];
                a0 += (float)v[0]; a1 += (float)v[1]; a2 += (float)v[2]; a3 += (float)v[3];
                a4 += (float)v[4]; a5 += (float)v[5]; a6 += (float)v[6]; a7 += (float)v[7];
            }
        }
    }
    acc[0] = a0 + b0; acc[1] = a1 + b1; acc[2] = a2 + b2; acc[3] = a3 + b3;
    acc[4] = a4 + b4; acc[5] = a5 + b5; acc[6] = a6 + b6; acc[7] = a7 + b7;
}

// ---------------- fused aggregate + GEMM (layers 2,3) ----------------

__global__ __launch_bounds__(256) void agg_gemm_kernel(
    const __half* __restrict__ ysIn, const int* __restrict__ rowptr,
    const int* __restrict__ col, const float* __restrict__ dinv,
    const float* __restrict__ bias, const __half* __restrict__ WhT,
    __half* __restrict__ ysOut, int M) {
    __shared__ __half lds_h[16 * PADH];
    int tid  = threadIdx.x;
    int wave = tid >> 6;
    int lane = tid & 63;
    int grp  = lane >> 4;
    int l16  = lane & 15;
    int rbase = blockIdx.x * 16;
    int lrow  = wave * 4 + grp;
    int row   = min(rbase + lrow, M - 1);

    float acc8[8];
    gather4(ysIn, rowptr, col, row, lane, acc8);

    float dv = dinv[row];
    float4 bb0 = ((const float4*)bias)[l16 * 2];
    float4 bb1 = ((const float4*)bias)[l16 * 2 + 1];
    half8 hv;
    hv[0] = (_Float16)fmaxf(bb0.x + dv * acc8[0], 0.f);
    hv[1] = (_Float16)fmaxf(bb0.y + dv * acc8[1], 0.f);
    hv[2] = (_Float16)fmaxf(bb0.z + dv * acc8[2], 0.f);
    hv[3] = (_Float16)fmaxf(bb0.w + dv * acc8[3], 0.f);
    hv[4] = (_Float16)fmaxf(bb1.x + dv * acc8[4], 0.f);
    hv[5] = (_Float16)fmaxf(bb1.y + dv * acc8[5], 0.f);
    hv[6] = (_Float16)fmaxf(bb1.z + dv * acc8[6], 0.f);
    hv[7] = (_Float16)fmaxf(bb1.w + dv * acc8[7], 0.f);
    ((half8*)(lds_h + (size_t)lrow * PADH))[l16] = hv;
    __syncthreads();

    int quad = lane >> 4;
    int t0   = wave * 2;
    f32x4 acc0 = (f32x4)0.0f, acc1 = (f32x4)0.0f;
    const __half* arow = lds_h + (size_t)l16 * PADH;
    #pragma unroll
    for (int ks = 0; ks < 4; ++ks) {
        int k0 = ks * 32 + quad * 8;
        half8 a  = *(const half8*)(arow + k0);
        half8 b0 = *(const half8*)(WhT + (size_t)((t0 + 0) * 16 + l16) * D + k0);
        half8 b1 = *(const half8*)(WhT + (size_t)((t0 + 1) * 16 + l16) * D + k0);
        acc0 = __builtin_amdgcn_mfma_f32_16x16x32_f16(a, b0, acc0, 0, 0, 0);
        acc1 = __builtin_amdgcn_mfma_f32_16x16x32_f16(a, b1, acc1, 0, 0, 0);
    }
    #pragma unroll
    for (int r = 0; r < 4; ++r) {
        int grow = rbase + quad * 4 + r;
        if (grow < M) {
            float dvr = dinv[grow];
            ysOut[(size_t)grow * D + (t0 + 0) * 16 + l16] = __float2half(acc0[r] * dvr);
            ysOut[(size_t)grow * D + (t0 + 1) * 16 + l16] = __float2half(acc1[r] * dvr);
        }
    }
}

// ---------------- final aggregate: out = b3 + dinv*(self+neighbors), fp32 ----------------

__global__ __launch_bounds__(256) void agg_final_kernel(
    const __half* __restrict__ ys, const int* __restrict__ rowptr,
    const int* __restrict__ col, const float* __restrict__ dinv,
    const float* __restrict__ b, float* __restrict__ out, int N) {
    int gwave = (blockIdx.x * blockDim.x + threadIdx.x) >> 6;
    int lane  = threadIdx.x & 63;
    int grp   = lane >> 4;
    int l16   = lane & 15;
    int rbase = gwave * 4;
    if (rbase >= N) return;
    int row = min(rbase + grp, N - 1);

    float acc8[8];
    gather4(ys, rowptr, col, row, lane, acc8);

    if (rbase + grp < N) {
        float dv = dinv[row];
        float4 bb0 = ((const float4*)b)[l16 * 2];
        float4 bb1 = ((const float4*)b)[l16 * 2 + 1];
        float4 r0, r1;
        r0.x = bb0.x + dv * acc8[0];
        r0.y = bb0.y + dv * acc8[1];
        r0.z = bb0.z + dv * acc8[2];
        r0.w = bb0.w + dv * acc8[3];
        r1.x = bb1.x + dv * acc8[4];
        r1.y = bb1.y + dv * acc8[5];
        r1.z = bb1.z + dv * acc8[6];
        r1.w = bb1.w + dv * acc8[7];
        float* op = out + (size_t)row * D + l16 * 8;
        ((float4*)op)[0] = r0;
        ((float4*)op)[1] = r1;
    }
}

// ---------------- fallback kernels (R8 path, used only if workspace too small) ----------------

__global__ void count_rank_kernel(const int* __restrict__ dst, int* __restrict__ cnt,
                                  int* __restrict__ rank, int E) {
    int e0 = (blockIdx.x * blockDim.x + threadIdx.x) * 8;
    if (e0 + 7 < E) {
        int4 da = *(const int4*)(dst + e0);
        int4 db = *(const int4*)(dst + e0 + 4);
        int4 ra, rb;
        ra.x = atomicAdd(&cnt[da.x], 1);
        ra.y = atomicAdd(&cnt[da.y], 1);
        ra.z = atomicAdd(&cnt[da.z], 1);
        ra.w = atomicAdd(&cnt[da.w], 1);
        rb.x = atomicAdd(&cnt[db.x], 1);
        rb.y = atomicAdd(&cnt[db.y], 1);
        rb.z = atomicAdd(&cnt[db.z], 1);
        rb.w = atomicAdd(&cnt[db.w], 1);
        *(int4*)(rank + e0)     = ra;
        *(int4*)(rank + e0 + 4) = rb;
    } else {
        for (int e = e0; e < E; ++e) rank[e] = atomicAdd(&cnt[dst[e]], 1);
    }
}

__global__ __launch_bounds__(256) void fill_gemm1_kernel(
    const int* __restrict__ src, const int* __restrict__ dst,
    const int* __restrict__ rank, const int* __restrict__ rowptr,
    int* __restrict__ col, int E, int fill_blocks, int N,
    const float* __restrict__ X, const __half* __restrict__ WhT,
    const float* __restrict__ dinv, __half* __restrict__ Y, int M) {
    int tid = threadIdx.x;
    if ((int)blockIdx.x < fill_blocks) {
        int shard = blockIdx.x & 7;
        int sub   = blockIdx.x >> 3;
        int nsub  = fill_blocks >> 3;
        int chunk = (N + 7) >> 3;
        int lo = shard * chunk;
        unsigned span = (unsigned)(min(lo + chunk, N) - lo);
        const int NO = (E + 7) / 8;
        for (int c = sub * 256 + tid; c < NO; c += nsub * 256) {
            int e0 = c * 8;
            if (e0 + 7 < E) {
                int4 da = *(const int4*)(dst + e0);
                int4 db = *(const int4*)(dst + e0 + 4);
                bool i0 = (unsigned)(da.x - lo) < span, i1 = (unsigned)(da.y - lo) < span;
                bool i2 = (unsigned)(da.z - lo) < span, i3 = (unsigned)(da.w - lo) < span;
                bool i4 = (unsigned)(db.x - lo) < span, i5 = (unsigned)(db.y - lo) < span;
                bool i6 = (unsigned)(db.z - lo) < span, i7 = (unsigned)(db.w - lo) < span;
                if (i0 | i1 | i2 | i3 | i4 | i5 | i6 | i7) {
                    int4 ra = *(const int4*)(rank + e0);
                    int4 rb = *(const int4*)(rank + e0 + 4);
                    int4 sa = *(const int4*)(src + e0);
                    int4 sb = *(const int4*)(src + e0 + 4);
                    if (i0) col[rowptr[da.x] + ra.x] = sa.x;
                    if (i1) col[rowptr[da.y] + ra.y] = sa.y;
                    if (i2) col[rowptr[da.z] + ra.z] = sa.z;
                    if (i3) col[rowptr[da.w] + ra.w] = sa.w;
                    if (i4) col[rowptr[db.x] + rb.x] = sb.x;
                    if (i5) col[rowptr[db.y] + rb.y] = sb.y;
                    if (i6) col[rowptr[db.z] + rb.z] = sb.z;
                    if (i7) col[rowptr[db.w] + rb.w] = sb.w;
                }
            } else {
                for (int e = e0; e < E; ++e) {
                    int d = dst[e];
                    if ((unsigned)(d - lo) < span) col[rowptr[d] + rank[e]] = src[e];
                }
            }
        }
        return;
    }
    int bid  = blockIdx.x - fill_blocks;
    int wave = tid >> 6;
    int lane = tid & 63;
    int quad = lane >> 4;
    int l16  = lane & 15;
    int m0   = bid * 64 + wave * 16;
    if (m0 >= M) return;

    f32x4 acc[8];
    #pragma unroll
    for (int t = 0; t < 8; ++t) acc[t] = (f32x4)0.0f;
    const float* xrow = X + (size_t)(m0 + l16) * D;
    #pragma unroll
    for (int ks = 0; ks < 4; ++ks) {
        int k0 = ks * 32 + quad * 8;
        float4 x0 = *(const float4*)(xrow + k0);
        float4 x1 = *(const float4*)(xrow + k0 + 4);
        half8 a;
        a[0] = (_Float16)x0.x; a[1] = (_Float16)x0.y;
        a[2] = (_Float16)x0.z; a[3] = (_Float16)x0.w;
        a[4] = (_Float16)x1.x; a[5] = (_Float16)x1.y;
        a[6] = (_Float16)x1.z; a[7] = (_Float16)x1.w;
        #pragma unroll
        for (int t = 0; t < 8; ++t) {
            half8 b = *(const half8*)(WhT + (size_t)(t * 16 + l16) * D + k0);
            acc[t] = __builtin_amdgcn_mfma_f32_16x16x32_f16(a, b, acc[t], 0, 0, 0);
        }
    }
    float4 dv = *(const float4*)(dinv + m0 + quad * 4);
    float dvs[4] = {dv.x, dv.y, dv.z, dv.w};
    #pragma unroll
    for (int t = 0; t < 8; ++t) {
        #pragma unroll
        for (int r = 0; r < 4; ++r) {
            int grow = m0 + quad * 4 + r;
            Y[(size_t)grow * D + t * 16 + l16] = __float2half(acc[t][r] * dvs[r]);
        }
    }
}

// ---------------- launch ----------------

extern "C" void kernel_launch(void* const* d_in, const int* in_sizes, int n_in,
                              void* d_out, int out_size, void* d_ws, size_t ws_size,
                              hipStream_t stream) {
    const float* x   = (const float*)d_in[0];
    const int*   ei  = (const int*)d_in[1];
    const float* W1  = (const float*)d_in[2];
    const float* b1  = (const float*)d_in[3];
    const float* W2  = (const float*)d_in[4];
    const float* b2  = (const float*)d_in[5];
    const float* W3  = (const float*)d_in[6];
    const float* b3  = (const float*)d_in[7];
    float* out = (float*)d_out;

    const int N = in_sizes[0] / D;
    const int E = in_sizes[1] / 2;
    const int* src = ei;
    const int* dst = ei + E;

    char* ws = (char*)d_ws;
    size_t off = 0;
    auto alloc = [&](size_t bytes) {
        void* p = ws + off;
        off = (off + bytes + 255) & ~(size_t)255;
        return p;
    };
    __half* ys    = (__half*)alloc((size_t)N * D * sizeof(__half));
    __half* hs    = (__half*)alloc((size_t)N * D * sizeof(__half));
    int*   cnt    = (int*)alloc((size_t)N * sizeof(int));
    int*   rowptr = (int*)alloc((size_t)(N + 1) * sizeof(int));
    float* dinv   = (float*)alloc((size_t)N * sizeof(float));
    int*   rank   = (int*)alloc((size_t)E * sizeof(int));
    int*   col    = (int*)alloc((size_t)E * sizeof(int));
    __half* WhT   = (__half*)alloc((size_t)3 * D * D * sizeof(__half));
    size_t base_need = off;
    float* ysf    = (float*)alloc((size_t)N * D * sizeof(float));   // fp32 unscaled X@W1
    size_t full_need = off;
    (void)n_in; (void)out_size; (void)base_need;

    const bool planA = (ws_size == 0) || (ws_size >= full_need);

    // 1. prep: W transpose/convert + cnt zero
    int prep_threads = (3 * D * D > N) ? 3 * D * D : N;
    prep_kernel<<<(prep_threads + 255) / 256, 256, 0, stream>>>(W1, W2, W3, WhT, cnt, N);

    const int NO = (E + 7) / 8;
    const int egrid = (NO + 255) / 256;
    const int gemm1_grid = (N + 63) / 64;
    const int FB = ((egrid + 7) / 8) * 8;

    if (planA) {
        // 2. count+rank || unscaled gemm1 -> ysf (one dispatch; atomics hidden under MFMA)
        count_gemm1_kernel<<<egrid + gemm1_grid, 256, 0, stream>>>(
            dst, cnt, rank, E, egrid, x, WhT, ysf, N);
        // 3. scan
        scan_kernel<<<1, 1024, 0, stream>>>(cnt, rowptr, dinv, N);
        // 4. sharded fill || ys = fp16(ysf * dinv)
        const int SB = 256;
        fill_scale_kernel<<<FB + SB, 256, 0, stream>>>(
            src, dst, rank, rowptr, col, E, FB, N, ysf, dinv, ys, SB);
    } else {
        // Fallback (R8 sequence)
        count_rank_kernel<<<egrid, 256, 0, stream>>>(dst, cnt, rank, E);
        scan_kernel<<<1, 1024, 0, stream>>>(cnt, rowptr, dinv, N);
        fill_gemm1_kernel<<<FB + gemm1_grid, 256, 0, stream>>>(
            src, dst, rank, rowptr, col, E, FB, N, x, WhT, dinv, ys, N);
    }

    // 5-6. fused aggregate+GEMM (quad-row, 16-deep): layer-2 (ys->hs), layer-3 (hs->ys)
    const int agg_gemm_grid = (N + 15) / 16;
    agg_gemm_kernel<<<agg_gemm_grid, 256, 0, stream>>>(ys, rowptr, col, dinv, b1, WhT + 16384, hs, N);
    agg_gemm_kernel<<<agg_gemm_grid, 256, 0, stream>>>(hs, rowptr, col, dinv, b2, WhT + 32768, ys, N);

    // 7. final aggregate (quad-row) -> fp32 out
    const int aggf_grid = (((N + 3) / 4) * 64 + 255) / 256;
    agg_final_kernel<<<aggf_grid, 256, 0, stream>>>(ys, rowptr, col, dinv, b3, out, N);
}

// Round 11
// 302.241 us; speedup vs baseline: 1.0268x; 1.0268x over previous
//
#include <hip/hip_runtime.h>
#include <hip/hip_fp16.h>
#include <math.h>

#define D 128
#define PADH 136  // LDS row stride in halves (272 B = 17*16: b128-aligned, 2-way bank alias only)

typedef __attribute__((ext_vector_type(8))) _Float16 half8;
typedef __attribute__((ext_vector_type(4))) float f32x4;

// ---------------- prep: WhT[l][n][k] = (half)Wl[k][n]  +  cnt zeroing ----------------

__global__ void prep_kernel(const float* __restrict__ W1, const float* __restrict__ W2,
                            const float* __restrict__ W3, __half* __restrict__ WhT,
                            int* __restrict__ cnt, int N) {
    int i = blockIdx.x * blockDim.x + threadIdx.x;
    if (i < 3 * D * D) {
        int l = i >> 14, j = i & 16383, n = j >> 7, k = j & 127;
        const float* W = (l == 0) ? W1 : (l == 1) ? W2 : W3;
        WhT[(size_t)i] = __float2half(W[(size_t)k * D + n]);
    }
    if (i < N) cnt[i] = 0;
}

// ---------------- graph build ----------------

// rank[e] = arrival order of edge e within its dst bucket; cnt[d] = in-degree.
// 2 edges/thread -> 1563 blocks (~24 waves/CU resident): enough in-flight
// device-scope atomics to hide the ~500-cycle L3 atomic latency.
// (R9 lesson: the old 8-edge/thread grid was 1.5 waves/SIMD -> latency-starved.)

__global__ void count_rank_kernel(const int* __restrict__ dst, int* __restrict__ cnt,
                                  int* __restrict__ rank, int E) {
    int e0 = (blockIdx.x * blockDim.x + threadIdx.x) * 2;
    if (e0 + 1 < E) {
        int2 d = *(const int2*)(dst + e0);
        int2 r;
        r.x = atomicAdd(&cnt[d.x], 1);
        r.y = atomicAdd(&cnt[d.y], 1);
        *(int2*)(rank + e0) = r;
    } else if (e0 < E) {
        rank[e0] = atomicAdd(&cnt[dst[e0]], 1);
    }
}

// single-block scan, one barrier pass: per-thread contiguous chunk, two vector sweeps.
__global__ __launch_bounds__(1024) void scan_kernel(const int* __restrict__ cnt,
                                                    int* __restrict__ rowptr,
                                                    float* __restrict__ dinv,
                                                    int N) {
    __shared__ int wsum[16];
    int tid  = threadIdx.x;
    int lane = tid & 63;
    int wid  = tid >> 6;
    int C = ((N + 4095) / 4096) * 4;
    int start = tid * C;
    int end   = start + C; if (end > N) end = N;

    int local = 0;
    int i = start;
    for (; i + 3 < end; i += 4) {
        int4 v = *(const int4*)(cnt + i);
        local += v.x + v.y + v.z + v.w;
    }
    for (; i < end; ++i) local += cnt[i];

    int sc = local;
    #pragma unroll
    for (int off = 1; off < 64; off <<= 1) {
        int t = __shfl_up(sc, off, 64);
        if (lane >= off) sc += t;
    }
    if (lane == 63) wsum[wid] = sc;
    __syncthreads();
    if (tid < 16) {
        int w = wsum[tid];
        #pragma unroll
        for (int off = 1; off < 16; off <<= 1) {
            int t = __shfl_up(w, off, 16);
            if (tid >= off) w += t;
        }
        wsum[tid] = w;
    }
    __syncthreads();
    int run = ((wid > 0) ? wsum[wid - 1] : 0) + (sc - local);

    i = start;
    for (; i + 3 < end; i += 4) {
        int4 v = *(const int4*)(cnt + i);
        int4 rp;
        rp.x = run; rp.y = rp.x + v.x; rp.z = rp.y + v.y; rp.w = rp.z + v.z;
        run = rp.w + v.w;
        *(int4*)(rowptr + i) = rp;
        float4 dv;
        dv.x = rsqrtf((float)v.x + 1.0f);
        dv.y = rsqrtf((float)v.y + 1.0f);
        dv.z = rsqrtf((float)v.z + 1.0f);
        dv.w = rsqrtf((float)v.w + 1.0f);
        *(float4*)(dinv + i) = dv;
    }
    for (; i < end; ++i) {
        int v = cnt[i];
        rowptr[i] = run; run += v;
        dinv[i] = rsqrtf((float)v + 1.0f);
    }
    if (tid == 0) rowptr[N] = wsum[15];
}

// ---------------- quad-row gather (R8 proven, 8-deep) ----------------
// Lanes split 4 groups x 16; group g owns one row, lane holds 8 halves (16B).
// One gather instruction fetches FOUR rows' 256B lines; 8-deep unroll keeps
// 32 row-lines in flight per wave.

__device__ __forceinline__ void gather4(const __half* __restrict__ g,
                                        const int* __restrict__ rowptr,
                                        const int* __restrict__ col,
                                        int row, int lane, float* __restrict__ acc) {
    int grp = lane >> 4;
    int l16 = lane & 15;
    int gb  = grp << 4;
    int s = rowptr[row], e = rowptr[row + 1];

    half8 hs = ((const half8*)(g + (size_t)row * D))[l16];
    float a0 = (float)hs[0], a1 = (float)hs[1], a2 = (float)hs[2], a3 = (float)hs[3];
    float a4 = (float)hs[4], a5 = (float)hs[5], a6 = (float)hs[6], a7 = (float)hs[7];
    float b0 = 0.f, b1 = 0.f, b2 = 0.f, b3 = 0.f, b4 = 0.f, b5 = 0.f, b6 = 0.f, b7 = 0.f;

    for (int base = s; base < e; base += 16) {
        int idx = base + l16;
        int myc = (idx < e) ? col[idx] : 0;
        int nb  = min(16, e - base);
        int j = 0;
        for (; j + 8 <= nb; j += 8) {
            int c0 = __shfl(myc, gb + j + 0), c1 = __shfl(myc, gb + j + 1);
            int c2 = __shfl(myc, gb + j + 2), c3 = __shfl(myc, gb + j + 3);
            int c4 = __shfl(myc, gb + j + 4), c5 = __shfl(myc, gb + j + 5);
            int c6 = __shfl(myc, gb + j + 6), c7 = __shfl(myc, gb + j + 7);
            half8 v0 = ((const half8*)(g + (size_t)c0 * D))[l16];
            half8 v1 = ((const half8*)(g + (size_t)c1 * D))[l16];
            half8 v2 = ((const half8*)(g + (size_t)c2 * D))[l16];
            half8 v3 = ((const half8*)(g + (size_t)c3 * D))[l16];
            half8 v4 = ((const half8*)(g + (size_t)c4 * D))[l16];
            half8 v5 = ((const half8*)(g + (size_t)c5 * D))[l16];
            half8 v6 = ((const half8*)(g + (size_t)c6 * D))[l16];
            half8 v7 = ((const half8*)(g + (size_t)c7 * D))[l16];
            a0 += (float)v0[0]; a1 += (float)v0[1]; a2 += (float)v0[2]; a3 += (float)v0[3];
            a4 += (float)v0[4]; a5 += (float)v0[5]; a6 += (float)v0[6]; a7 += (float)v0[7];
            b0 += (float)v1[0]; b1 += (float)v1[1]; b2 += (float)v1[2]; b3 += (float)v1[3];
            b4 += (float)v1[4]; b5 += (float)v1[5]; b6 += (float)v1[6]; b7 += (float)v1[7];
            a0 += (float)v2[0]; a1 += (float)v2[1]; a2 += (float)v2[2]; a3 += (float)v2[3];
            a4 += (float)v2[4]; a5 += (float)v2[5]; a6 += (float)v2[6]; a7 += (float)v2[7];
            b0 += (float)v3[0]; b1 += (float)v3[1]; b2 += (float)v3[2]; b3 += (float)v3[3];
            b4 += (float)v3[4]; b5 += (float)v3[5]; b6 += (float)v3[6]; b7 += (float)v3[7];
            a0 += (float)v4[0]; a1 += (float)v4[1]; a2 += (float)v4[2]; a3 += (float)v4[3];
            a4 += (float)v4[4]; a5 += (float)v4[5]; a6 += (float)v4[6]; a7 += (float)v4[7];
            b0 += (float)v5[0]; b1 += (float)v5[1]; b2 += (float)v5[2]; b3 += (float)v5[3];
            b4 += (float)v5[4]; b5 += (float)v5[5]; b6 += (float)v5[6]; b7 += (float)v5[7];
            a0 += (float)v6[0]; a1 += (float)v6[1]; a2 += (float)v6[2]; a3 += (float)v6[3];
            a4 += (float)v6[4]; a5 += (float)v6[5]; a6 += (float)v6[6]; a7 += (float)v6[7];
            b0 += (float)v7[0]; b1 += (float)v7[1]; b2 += (float)v7[2]; b3 += (float)v7[3];
            b4 += (float)v7[4]; b5 += (float)v7[5]; b6 += (float)v7[6]; b7 += (float)v7[7];
        }
        for (; j + 4 <= nb; j += 4) {
            int c0 = __shfl(myc, gb + j + 0), c1 = __shfl(myc, gb + j + 1);
            int c2 = __shfl(myc, gb + j + 2), c3 = __shfl(myc, gb + j + 3);
            half8 v0 = ((const half8*)(g + (size_t)c0 * D))[l16];
            half8 v1 = ((const half8*)(g + (size_t)c1 * D))[l16];
            half8 v2 = ((const half8*)(g + (size_t)c2 * D))[l16];
            half8 v3 = ((const half8*)(g + (size_t)c3 * D))[l16];
            a0 += (float)v0[0]; a1 += (float)v0[1]; a2 += (float)v0[2]; a3 += (float)v0[3];
            a4 += (float)v0[4]; a5 += (float)v0[5]; a6 += (float)v0[6]; a7 += (float)v0[7];
            b0 += (float)v1[0]; b1 += (float)v1[1]; b2 += (float)v1[2]; b3 += (float)v1[3];
            b4 += (float)v1[4]; b5 += (float)v1[5]; b6 += (float)v1[6]; b7 += (float)v1[7];
            a0 += (float)v2[0]; a1 += (float)v2[1]; a2 += (float)v2[2]; a3 += (float)v2[3];
            a4 += (float)v2[4]; a5 += (float)v2[5]; a6 += (float)v2[6]; a7 += (float)v2[7];
            b0 += (float)v3[0]; b1 += (float)v3[1]; b2 += (float)v3[2]; b3 += (float)v3[3];
            b4 += (float)v3[4]; b5 += (float)v3[5]; b6 += (float)v3[6]; b7 += (float)v3[7];
        }
        for (; j < nb; ++j) {
            int c = __shfl(myc, gb + j);
            half8 v = ((const half8*)(g + (size_t)c * D))[l16];
            a0 += (float)v[0]; a1 += (float)v[1]; a2 += (float)v[2]; a3 += (float)v[3];
            a4 += (float)v[4]; a5 += (float)v[5]; a6 += (float)v[6]; a7 += (float)v[7];
        }
    }
    acc[0] = a0 + b0; acc[1] = a1 + b1; acc[2] = a2 + b2; acc[3] = a3 + b3;
    acc[4] = a4 + b4; acc[5] = a5 + b5; acc[6] = a6 + b6; acc[7] = a7 + b7;
}

// ---------------- fill + gemm1 (fused by block range) ----------------
// fill: XCD-SHARDED by dst-range: shard = bid&7 rides the round-robin block->XCD
// map so each col line is written from exactly ONE XCD (kills write ping-pong).
// Each shard re-reads the edge arrays sequentially (L3-served).

__global__ __launch_bounds__(256) void fill_gemm1_kernel(
    const int* __restrict__ src, const int* __restrict__ dst,
    const int* __restrict__ rank, const int* __restrict__ rowptr,
    int* __restrict__ col, int E, int fill_blocks, int N,
    const float* __restrict__ X, const __half* __restrict__ WhT,
    const float* __restrict__ dinv, __half* __restrict__ Y, int M) {
    int tid = threadIdx.x;
    if ((int)blockIdx.x < fill_blocks) {
        int shard = blockIdx.x & 7;
        int sub   = blockIdx.x >> 3;
        int nsub  = fill_blocks >> 3;
        int chunk = (N + 7) >> 3;
        int lo = shard * chunk;
        unsigned span = (unsigned)(min(lo + chunk, N) - lo);
        const int NO = (E + 7) / 8;
        for (int c = sub * 256 + tid; c < NO; c += nsub * 256) {
            int e0 = c * 8;
            if (e0 + 7 < E) {
                int4 da = *(const int4*)(dst + e0);
                int4 db = *(const int4*)(dst + e0 + 4);
                bool i0 = (unsigned)(da.x - lo) < span, i1 = (unsigned)(da.y - lo) < span;
                bool i2 = (unsigned)(da.z - lo) < span, i3 = (unsigned)(da.w - lo) < span;
                bool i4 = (unsigned)(db.x - lo) < span, i5 = (unsigned)(db.y - lo) < span;
                bool i6 = (unsigned)(db.z - lo) < span, i7 = (unsigned)(db.w - lo) < span;
                if (i0 | i1 | i2 | i3 | i4 | i5 | i6 | i7) {
                    int4 ra = *(const int4*)(rank + e0);
                    int4 rb = *(const int4*)(rank + e0 + 4);
                    int4 sa = *(const int4*)(src + e0);
                    int4 sb = *(const int4*)(src + e0 + 4);
                    if (i0) col[rowptr[da.x] + ra.x] = sa.x;
                    if (i1) col[rowptr[da.y] + ra.y] = sa.y;
                    if (i2) col[rowptr[da.z] + ra.z] = sa.z;
                    if (i3) col[rowptr[da.w] + ra.w] = sa.w;
                    if (i4) col[rowptr[db.x] + rb.x] = sb.x;
                    if (i5) col[rowptr[db.y] + rb.y] = sb.y;
                    if (i6) col[rowptr[db.z] + rb.z] = sb.z;
                    if (i7) col[rowptr[db.w] + rb.w] = sb.w;
                }
            } else {
                for (int e = e0; e < E; ++e) {
                    int d = dst[e];
                    if ((unsigned)(d - lo) < span) col[rowptr[d] + rank[e]] = src[e];
                }
            }
        }
        return;
    }
    int bid  = blockIdx.x - fill_blocks;
    int wave = tid >> 6;
    int lane = tid & 63;
    int quad = lane >> 4;
    int l16  = lane & 15;
    int m0   = bid * 64 + wave * 16;
    if (m0 >= M) return;

    f32x4 acc[8];
    #pragma unroll
    for (int t = 0; t < 8; ++t) acc[t] = (f32x4)0.0f;
    const float* xrow = X + (size_t)(m0 + l16) * D;
    #pragma unroll
    for (int ks = 0; ks < 4; ++ks) {
        int k0 = ks * 32 + quad * 8;
        float4 x0 = *(const float4*)(xrow + k0);
        float4 x1 = *(const float4*)(xrow + k0 + 4);
        half8 a;
        a[0] = (_Float16)x0.x; a[1] = (_Float16)x0.y;
        a[2] = (_Float16)x0.z; a[3] = (_Float16)x0.w;
        a[4] = (_Float16)x1.x; a[5] = (_Float16)x1.y;
        a[6] = (_Float16)x1.z; a[7] = (_Float16)x1.w;
        #pragma unroll
        for (int t = 0; t < 8; ++t) {
            half8 b = *(const half8*)(WhT + (size_t)(t * 16 + l16) * D + k0);
            acc[t] = __builtin_amdgcn_mfma_f32_16x16x32_f16(a, b, acc[t], 0, 0, 0);
        }
    }
    float4 dv = *(const float4*)(dinv + m0 + quad * 4);
    float dvs[4] = {dv.x, dv.y, dv.z, dv.w};
    #pragma unroll
    for (int t = 0; t < 8; ++t) {
        #pragma unroll
        for (int r = 0; r < 4; ++r) {
            int grow = m0 + quad * 4 + r;
            Y[(size_t)grow * D + t * 16 + l16] = __float2half(acc[t][r] * dvs[r]);
        }
    }
}

// ---------------- fused aggregate + GEMM (layers 2,3) ----------------
// 256 threads / 4 waves / 16 rows; each wave aggregates its 4 rows in ONE
// quad-row gather call, then the GEMM phase computes 16x128.

__global__ __launch_bounds__(256) void agg_gemm_kernel(
    const __half* __restrict__ ysIn, const int* __restrict__ rowptr,
    const int* __restrict__ col, const float* __restrict__ dinv,
    const float* __restrict__ bias, const __half* __restrict__ WhT,
    __half* __restrict__ ysOut, int M) {
    __shared__ __half lds_h[16 * PADH];
    int tid  = threadIdx.x;
    int wave = tid >> 6;
    int lane = tid & 63;
    int grp  = lane >> 4;
    int l16  = lane & 15;
    int rbase = blockIdx.x * 16;
    int lrow  = wave * 4 + grp;
    int row   = min(rbase + lrow, M - 1);

    float acc8[8];
    gather4(ysIn, rowptr, col, row, lane, acc8);

    float dv = dinv[row];
    float4 bb0 = ((const float4*)bias)[l16 * 2];
    float4 bb1 = ((const float4*)bias)[l16 * 2 + 1];
    half8 hv;
    hv[0] = (_Float16)fmaxf(bb0.x + dv * acc8[0], 0.f);
    hv[1] = (_Float16)fmaxf(bb0.y + dv * acc8[1], 0.f);
    hv[2] = (_Float16)fmaxf(bb0.z + dv * acc8[2], 0.f);
    hv[3] = (_Float16)fmaxf(bb0.w + dv * acc8[3], 0.f);
    hv[4] = (_Float16)fmaxf(bb1.x + dv * acc8[4], 0.f);
    hv[5] = (_Float16)fmaxf(bb1.y + dv * acc8[5], 0.f);
    hv[6] = (_Float16)fmaxf(bb1.z + dv * acc8[6], 0.f);
    hv[7] = (_Float16)fmaxf(bb1.w + dv * acc8[7], 0.f);
    ((half8*)(lds_h + (size_t)lrow * PADH))[l16] = hv;
    __syncthreads();

    int quad = lane >> 4;
    int t0   = wave * 2;
    f32x4 acc0 = (f32x4)0.0f, acc1 = (f32x4)0.0f;
    const __half* arow = lds_h + (size_t)l16 * PADH;
    #pragma unroll
    for (int ks = 0; ks < 4; ++ks) {
        int k0 = ks * 32 + quad * 8;
        half8 a  = *(const half8*)(arow + k0);
        half8 b0 = *(const half8*)(WhT + (size_t)((t0 + 0) * 16 + l16) * D + k0);
        half8 b1 = *(const half8*)(WhT + (size_t)((t0 + 1) * 16 + l16) * D + k0);
        acc0 = __builtin_amdgcn_mfma_f32_16x16x32_f16(a, b0, acc0, 0, 0, 0);
        acc1 = __builtin_amdgcn_mfma_f32_16x16x32_f16(a, b1, acc1, 0, 0, 0);
    }
    #pragma unroll
    for (int r = 0; r < 4; ++r) {
        int grow = rbase + quad * 4 + r;
        if (grow < M) {
            float dvr = dinv[grow];
            ysOut[(size_t)grow * D + (t0 + 0) * 16 + l16] = __float2half(acc0[r] * dvr);
            ysOut[(size_t)grow * D + (t0 + 1) * 16 + l16] = __float2half(acc1[r] * dvr);
        }
    }
}

// ---------------- final aggregate: out = b3 + dinv*(self+neighbors), fp32 ----------------
// quad-row: each wave handles 4 rows via one gather4 call.

__global__ __launch_bounds__(256) void agg_final_kernel(
    const __half* __restrict__ ys, const int* __restrict__ rowptr,
    const int* __restrict__ col, const float* __restrict__ dinv,
    const float* __restrict__ b, float* __restrict__ out, int N) {
    int gwave = (blockIdx.x * blockDim.x + threadIdx.x) >> 6;
    int lane  = threadIdx.x & 63;
    int grp   = lane >> 4;
    int l16   = lane & 15;
    int rbase = gwave * 4;
    if (rbase >= N) return;
    int row = min(rbase + grp, N - 1);

    float acc8[8];
    gather4(ys, rowptr, col, row, lane, acc8);

    if (rbase + grp < N) {
        float dv = dinv[row];
        float4 bb0 = ((const float4*)b)[l16 * 2];
        float4 bb1 = ((const float4*)b)[l16 * 2 + 1];
        float4 r0, r1;
        r0.x = bb0.x + dv * acc8[0];
        r0.y = bb0.y + dv * acc8[1];
        r0.z = bb0.z + dv * acc8[2];
        r0.w = bb0.w + dv * acc8[3];
        r1.x = bb1.x + dv * acc8[4];
        r1.y = bb1.y + dv * acc8[5];
        r1.z = bb1.z + dv * acc8[6];
        r1.w = bb1.w + dv * acc8[7];
        float* op = out + (size_t)row * D + l16 * 8;
        ((float4*)op)[0] = r0;
        ((float4*)op)[1] = r1;
    }
}

// ---------------- launch ----------------

extern "C" void kernel_launch(void* const* d_in, const int* in_sizes, int n_in,
                              void* d_out, int out_size, void* d_ws, size_t ws_size,
                              hipStream_t stream) {
    const float* x   = (const float*)d_in[0];
    const int*   ei  = (const int*)d_in[1];
    const float* W1  = (const float*)d_in[2];
    const float* b1  = (const float*)d_in[3];
    const float* W2  = (const float*)d_in[4];
    const float* b2  = (const float*)d_in[5];
    const float* W3  = (const float*)d_in[6];
    const float* b3  = (const float*)d_in[7];
    float* out = (float*)d_out;

    const int N = in_sizes[0] / D;
    const int E = in_sizes[1] / 2;
    const int* src = ei;
    const int* dst = ei + E;

    char* ws = (char*)d_ws;
    size_t off = 0;
    auto alloc = [&](size_t bytes) {
        void* p = ws + off;
        off = (off + bytes + 255) & ~(size_t)255;
        return p;
    };
    __half* ys    = (__half*)alloc((size_t)N * D * sizeof(__half));
    __half* hs    = (__half*)alloc((size_t)N * D * sizeof(__half));
    int*   cnt    = (int*)alloc((size_t)N * sizeof(int));
    int*   rowptr = (int*)alloc((size_t)(N + 1) * sizeof(int));
    float* dinv   = (float*)alloc((size_t)N * sizeof(float));
    int*   rank   = (int*)alloc((size_t)E * sizeof(int));
    int*   col    = (int*)alloc((size_t)E * sizeof(int));
    __half* WhT   = (__half*)alloc((size_t)3 * D * D * sizeof(__half));
    (void)ws_size; (void)n_in; (void)out_size;

    // 1. prep: W transpose/convert + cnt zero
    int prep_threads = (3 * D * D > N) ? 3 * D * D : N;
    prep_kernel<<<(prep_threads + 255) / 256, 256, 0, stream>>>(W1, W2, W3, WhT, cnt, N);

    // 2-3. count+rank (2 edges/thread -> ~24 waves/CU for atomic latency hiding), scan
    const int cgrid = ((E + 1) / 2 + 255) / 256;
    count_rank_kernel<<<cgrid, 256, 0, stream>>>(dst, cnt, rank, E);
    scan_kernel<<<1, 1024, 0, stream>>>(cnt, rowptr, dinv, N);

    // 4. sharded fill + gemm1 fused (fill blocks: 8 shards x 98 sub-blocks)
    const int FB = 784;
    const int gemm1_grid = (N + 63) / 64;
    fill_gemm1_kernel<<<FB + gemm1_grid, 256, 0, stream>>>(
        src, dst, rank, rowptr, col, E, FB, N, x, WhT, dinv, ys, N);

    // 5-6. fused aggregate+GEMM with quad-row gather: layer-2 (ys->hs), layer-3 (hs->ys)
    const int agg_gemm_grid = (N + 15) / 16;
    agg_gemm_kernel<<<agg_gemm_grid, 256, 0, stream>>>(ys, rowptr, col, dinv, b1, WhT + 16384, hs, N);
    agg_gemm_kernel<<<agg_gemm_grid, 256, 0, stream>>>(hs, rowptr, col, dinv, b2, WhT + 32768, ys, N);

    // 7. final aggregate (quad-row) -> fp32 out
    const int aggf_grid = (((N + 3) / 4) * 64 + 255) / 256;
    agg_final_kernel<<<aggf_grid, 256, 0, stream>>>(ys, rowptr, col, dinv, b3, out, N);
}